// Round 16
// baseline (429.698 us; speedup 1.0000x reference)
//
#include <hip/hip_runtime.h>

// ---------------------------------------------------------------------------
// HeterogeneousNormalizedAttentionBlock on MI355X (gfx950)
// B=4, LQ=LK=8192, E=256, H=8, D=32, NF=2, NE=4, HID=256;  M = B*LQ = 32768
// ---------------------------------------------------------------------------

typedef unsigned short u16;
typedef __attribute__((ext_vector_type(8))) short   bs8;    // 8 x bf16
typedef __attribute__((ext_vector_type(4))) float   f32x4;
typedef __attribute__((ext_vector_type(16))) float  f32x16;

__device__ __forceinline__ float bf2f(u16 u) {
  union { float f; unsigned i; } c; c.i = ((unsigned)u) << 16; return c.f;
}
__device__ __forceinline__ u16 f2bf(float f) {
  union { float f; unsigned i; } c; c.f = f;
  unsigned x = c.i;
  return (u16)((x + 0x7fffu + ((x >> 16) & 1u)) >> 16);   // RNE
}
__device__ __forceinline__ unsigned pack2(float a, float b) {
  return (unsigned)f2bf(a) | ((unsigned)f2bf(b) << 16);
}
__device__ __forceinline__ float gelu_f(float x) {
  const float t = x * (0.7978845608f + 0.0356774081f * x * x);
  return x * __builtin_amdgcn_rcpf(1.f + __expf(-2.f * t));
}

#define EPI_PLAIN 0
#define EPI_QSM   4   // feature-dim softmax over 32-col head groups

// ---------------------------------------------------------------------------
// Attention-side GEMM: C(M,256) = epi(A(M,256) @ W(256,256)^T + bias)
// BM=64, BN=128, BK=64, 4 waves (2x2), wave 32x64.  Grid (512,2), 4 blk/CU.
// ---------------------------------------------------------------------------
template <bool AF32, int EPI>
__global__ __launch_bounds__(256, 4) void gemm256(
    const void* __restrict__ Ain, const u16* __restrict__ W,
    const float* __restrict__ bias, u16* __restrict__ outb) {
  __shared__ int4 ash[512];    // 64 x 64 bf16, swizzled
  __shared__ int4 wsh[1024];   // 128 x 64 bf16, swizzled
  const int tid = threadIdx.x;
  const int m0 = blockIdx.x * 64, n0 = blockIdx.y * 128;
  const int wave = tid >> 6, lane = tid & 63;
  const int wm = (wave >> 1) * 32, wn = (wave & 1) * 64;
  const int lr = lane & 15, lk = lane >> 4;
  f32x4 acc[2][4];
#pragma unroll
  for (int m = 0; m < 2; ++m)
#pragma unroll
    for (int n = 0; n < 4; ++n) acc[m][n] = f32x4{0.f, 0.f, 0.f, 0.f};

  const float* Af = (const float*)Ain;
  const u16*   Ab = (const u16*)Ain;

  for (int kt = 0; kt < 4; ++kt) {
    const int k0 = kt * 64;
    if (kt) __syncthreads();
#pragma unroll
    for (int it = 0; it < 2; ++it) {   // A tile 64x64
      const int s = tid + it * 256;
      const int row = s >> 3, c16 = s & 7;
      const int dst = (row << 3) | (c16 ^ (row & 7));
      const long src = (long)(m0 + row) * 256 + k0 + c16 * 8;
      int4 val;
      if constexpr (AF32) {
        const float4* p = (const float4*)(Af + src);
        const float4 x = p[0], y = p[1];
        val.x = pack2(x.x, x.y); val.y = pack2(x.z, x.w);
        val.z = pack2(y.x, y.y); val.w = pack2(y.z, y.w);
      } else {
        val = *(const int4*)(Ab + src);
      }
      ash[dst] = val;
    }
#pragma unroll
    for (int it = 0; it < 4; ++it) {   // W tile 128x64
      const int s = tid + it * 256;
      const int row = s >> 3, c16 = s & 7;
      const int dst = (row << 3) | (c16 ^ (row & 7));
      wsh[dst] = *(const int4*)(W + (long)(n0 + row) * 256 + k0 + c16 * 8);
    }
    __syncthreads();
#pragma unroll
    for (int kk = 0; kk < 2; ++kk) {
      bs8 af[2], wf[4];
#pragma unroll
      for (int m = 0; m < 2; ++m) {
        const int row = wm + m * 16 + lr;
        af[m] = *(const bs8*)&ash[(row << 3) | ((kk * 4 + lk) ^ (row & 7))];
      }
#pragma unroll
      for (int n = 0; n < 4; ++n) {
        const int row = wn + n * 16 + lr;
        wf[n] = *(const bs8*)&wsh[(row << 3) | ((kk * 4 + lk) ^ (row & 7))];
      }
#pragma unroll
      for (int m = 0; m < 2; ++m)
#pragma unroll
        for (int n = 0; n < 4; ++n)
          acc[m][n] = __builtin_amdgcn_mfma_f32_16x16x32_bf16(af[m], wf[n],
                                                              acc[m][n], 0, 0, 0);
    }
  }
  // ---- epilogue ----
  if constexpr (EPI == EPI_QSM) {
#pragma unroll
    for (int m = 0; m < 2; ++m) {
      const int rb = m0 + wm + m * 16 + lk * 4;
#pragma unroll
      for (int j = 0; j < 4; ++j) {
#pragma unroll
        for (int hh = 0; hh < 2; ++hh) {
          const int c0 = n0 + wn + (2 * hh) * 16 + lr;
          const float p0 = __expf(acc[m][2 * hh][j] + bias[c0]);
          const float p1 = __expf(acc[m][2 * hh + 1][j] + bias[c0 + 16]);
          float s = p0 + p1;
#pragma unroll
          for (int o = 8; o >= 1; o >>= 1) s += __shfl_xor(s, o);
          const float inv = 1.0f / s;
          outb[(long)(rb + j) * 256 + c0]      = f2bf(p0 * inv);
          outb[(long)(rb + j) * 256 + c0 + 16] = f2bf(p1 * inv);
        }
      }
    }
  } else {
#pragma unroll
    for (int m = 0; m < 2; ++m) {
      const int rb = m0 + wm + m * 16 + lk * 4;
#pragma unroll
      for (int n = 0; n < 4; ++n) {
        const int gc = n0 + wn + n * 16 + lr;
        const float bv = bias[gc];
#pragma unroll
        for (int j = 0; j < 4; ++j)
          outb[(long)(rb + j) * 256 + gc] = f2bf(acc[m][n][j] + bv);
      }
    }
  }
}

// ---------------------------------------------------------------------------
// ffn4: fused {Wo projection, 4-expert 3-layer FFN, combine, residual}.
// BM=64 (grid 512), 1024 threads = 16 waves, wave tile 64M x 16N (one
// N-group per wave) -> W L2 redundancy 1x (16 waves x 8KB = |W| per layer).
// Proj layer: xsh = Xin @ Wo^T + bP (no gelu), then expert loop.
// W from wave-contiguous WX[s][ng(16)][kt(8)][lane][8]; wf register dbuf;
// setprio around MFMA (T5).  xsh+hsh = 64KB, 2 blocks/CU (thread-capped max).
// ---------------------------------------------------------------------------
__global__ __launch_bounds__(1024, 4) void ffn4(
    const u16* __restrict__ Xin, const u16* __restrict__ WX,
    int wPslot, int wbase, const float* __restrict__ bP,
    const float* __restrict__ b1, const float* __restrict__ b2,
    const float* __restrict__ b3, const float* __restrict__ scores,
    const float* __restrict__ csrc, float* __restrict__ outf) {
  __shared__ int4 xsh[2048];   // 32KB: x (proj output) 64x256, chunk-XOR8
  __shared__ int4 hsh[2048];   // 32KB: Xin staging, then h (in-place)
  const int tid = threadIdx.x, wave = tid >> 6, lane = tid & 63;
  const int ng = wave;               // N-group: cols ng*16 .. ng*16+15
  const int lr = lane & 15, lk = lane >> 4;
  const int col = ng * 16 + lr;      // this thread's output column
  const long m0 = (long)blockIdx.x * 64;

  // stage Xin (64 x 256 bf16) into hsh
#pragma unroll
  for (int it = 0; it < 2; ++it) {
    const int s = tid + it * 1024;
    const int row = s >> 5, c8 = s & 31;
    const int cs = (c8 & 24) | ((c8 ^ row) & 7);
    hsh[row * 32 + cs] = *(const int4*)(Xin + (m0 + row) * 256 + c8 * 8);
  }
  __syncthreads();

  f32x4 acc[4];

  // ---- proj layer: x = Xin @ Wo^T + bP  -> xsh ----
  {
    const u16* wp = WX + (((long)wPslot) << 16) + (ng << 12) + lane * 8;
#pragma unroll
    for (int m = 0; m < 4; ++m) acc[m] = f32x4{0.f, 0.f, 0.f, 0.f};
    bs8 wf, wfn;
    wf = *(const bs8*)(wp);
#pragma unroll
    for (int kt = 0; kt < 8; ++kt) {
      if (kt < 7) wfn = *(const bs8*)(wp + (kt + 1) * 512);
      bs8 af[4];
      const int c8 = kt * 4 + lk;
#pragma unroll
      for (int m = 0; m < 4; ++m) {
        const int row = m * 16 + lr;
        const int cs = (c8 & 24) | ((c8 ^ row) & 7);
        af[m] = *(const bs8*)&hsh[row * 32 + cs];
      }
      __builtin_amdgcn_s_setprio(1);
#pragma unroll
      for (int m = 0; m < 4; ++m)
        acc[m] = __builtin_amdgcn_mfma_f32_16x16x32_bf16(af[m], wf, acc[m],
                                                         0, 0, 0);
      __builtin_amdgcn_s_setprio(0);
      wf = wfn;
    }
    __syncthreads();  // all hsh reads done (also guards xsh publish below)
    const float bv = bP[col];
    u16* xp = (u16*)xsh;
    const int c8w = col >> 3;
#pragma unroll
    for (int m = 0; m < 4; ++m)
#pragma unroll
      for (int j = 0; j < 4; ++j) {
        const int row = m * 16 + lk * 4 + j;
        const int cs = (c8w & 24) | ((c8w ^ row) & 7);
        xp[row * 256 + cs * 8 + (col & 7)] = f2bf(acc[m][j] + bv);
      }
    __syncthreads();  // xsh visible to all waves
  }

  f32x4 oacc[4];
#pragma unroll
  for (int m = 0; m < 4; ++m) oacc[m] = f32x4{0.f, 0.f, 0.f, 0.f};

  for (int e = 0; e < 4; ++e) {
#pragma unroll 1
    for (int l = 0; l < 3; ++l) {
      const u16* wp = WX + (((long)(wbase + l * 4 + e)) << 16) +
                      (ng << 12) + lane * 8;
      const int4* asrc = (l == 0) ? xsh : hsh;
#pragma unroll
      for (int m = 0; m < 4; ++m) acc[m] = f32x4{0.f, 0.f, 0.f, 0.f};
      bs8 wf, wfn;
      wf = *(const bs8*)(wp);
#pragma unroll
      for (int kt = 0; kt < 8; ++kt) {
        if (kt < 7) wfn = *(const bs8*)(wp + (kt + 1) * 512);
        bs8 af[4];
        const int c8 = kt * 4 + lk;
#pragma unroll
        for (int m = 0; m < 4; ++m) {
          const int row = m * 16 + lr;
          const int cs = (c8 & 24) | ((c8 ^ row) & 7);
          af[m] = *(const bs8*)&asrc[row * 32 + cs];
        }
        __builtin_amdgcn_s_setprio(1);
#pragma unroll
        for (int m = 0; m < 4; ++m)
          acc[m] = __builtin_amdgcn_mfma_f32_16x16x32_bf16(af[m], wf, acc[m],
                                                           0, 0, 0);
        __builtin_amdgcn_s_setprio(0);
        wf = wfn;
      }
      if (l < 2) {
        __syncthreads();   // all asrc reads done before hsh overwrite
        const float bv = (l == 0 ? b1 : b2)[e * 256 + col];
        u16* hp = (u16*)hsh;
        const int c8w = col >> 3;
#pragma unroll
        for (int m = 0; m < 4; ++m)
#pragma unroll
          for (int j = 0; j < 4; ++j) {
            const int row = m * 16 + lk * 4 + j;
            const int cs = (c8w & 24) | ((c8w ^ row) & 7);
            hp[row * 256 + cs * 8 + (col & 7)] =
                f2bf(gelu_f(acc[m][j] + bv));
          }
        __syncthreads();   // hsh visible to next layer
      } else {  // + b3, score-weighted accumulate (registers only)
        const float b3v = b3[e * 256 + col];
#pragma unroll
        for (int m = 0; m < 4; ++m) {
#pragma unroll
          for (int j = 0; j < 4; ++j) {
            const float sc = scores[(m0 + m * 16 + lk * 4 + j) * 4 + e];
            oacc[m][j] += sc * (acc[m][j] + b3v);
          }
        }
      }
    }
  }
  // ---- epilogue: out = csrc + oacc ----
#pragma unroll
  for (int m = 0; m < 4; ++m) {
#pragma unroll
    for (int j = 0; j < 4; ++j) {
      const long idx = (m0 + m * 16 + lk * 4 + j) * 256 + col;
      outf[idx] = csrc[idx] + oacc[m][j];
    }
  }
}

// ---------------------------------------------------------------------------
// kvstats (merged-f): fused {K-proj, V-proj, K-softmax, per-head stats}.
// blockIdx.y = fb = f*4 + b; per-f pointers passed explicitly.
// ---------------------------------------------------------------------------
__global__ __launch_bounds__(1024, 4) void kvstats(
    const float* __restrict__ A0, const float* __restrict__ A1,
    const u16* __restrict__ Wk0, const u16* __restrict__ Wk1,
    const u16* __restrict__ Wv0, const u16* __restrict__ Wv1,
    const float* __restrict__ bk0, const float* __restrict__ bk1,
    const float* __restrict__ bv0, const float* __restrict__ bv1,
    float* __restrict__ pks, float* __restrict__ ptm) {
  __shared__ __align__(16) char smem[73728];
  int4* ash  = (int4*)smem;        // 512 slots  (64x64 bf16)
  int4* wksh = ash + 512;          // 2048 slots (256x64)
  int4* wvsh = wksh + 2048;        // 2048 slots
  u16* KnT = (u16*)smem;           // [256][72] bf16 (transposed, padded)
  u16* VT  = KnT + 256 * 72;
  const int tid = threadIdx.x;
  const int wave = tid >> 6, lane = tid & 63;
  const int lr = lane & 15, lk = lane >> 4;
  const int kvsel = wave >> 3, w3 = wave & 7;
  const int wm = (w3 >> 2) * 32, wn = (w3 & 3) * 64;
  const int fb = blockIdx.y, ch = blockIdx.x;
  const int f = fb >> 2, b = fb & 3;
  const float* Ain = f ? A1 : A0;
  const u16* Wk = f ? Wk1 : Wk0;
  const u16* Wv = f ? Wv1 : Wv0;
  const float* bk = f ? bk1 : bk0;
  const float* bv = f ? bv1 : bv0;
  const long r0 = (long)b * 8192 + (long)ch * 64;

  f32x4 acc[2][4];
#pragma unroll
  for (int m = 0; m < 2; ++m)
#pragma unroll
    for (int n = 0; n < 4; ++n) acc[m][n] = f32x4{0.f, 0.f, 0.f, 0.f};

  for (int kt = 0; kt < 4; ++kt) {
    const int k0 = kt * 64;
    if (kt) __syncthreads();
    if (tid < 512) {  // A tile 64x64 fp32 -> bf16
      const int row = tid >> 3, c16 = tid & 7;
      const int dst = (row << 3) | (c16 ^ (row & 7));
      const float4* p = (const float4*)(Ain + (r0 + row) * 256 + k0 + c16 * 8);
      const float4 x = p[0], y = p[1];
      int4 val;
      val.x = pack2(x.x, x.y); val.y = pack2(x.z, x.w);
      val.z = pack2(y.x, y.y); val.w = pack2(y.z, y.w);
      ash[dst] = val;
    }
#pragma unroll
    for (int it = 0; it < 2; ++it) {  // Wk + Wv tiles 256x64
      const int s = tid + it * 1024;
      const int row = s >> 3, c16 = s & 7;
      const int dst = (row << 3) | (c16 ^ (row & 7));
      wksh[dst] = *(const int4*)(Wk + (long)row * 256 + k0 + c16 * 8);
      wvsh[dst] = *(const int4*)(Wv + (long)row * 256 + k0 + c16 * 8);
    }
    __syncthreads();
    const int4* wsh = kvsel ? wvsh : wksh;
#pragma unroll
    for (int kk = 0; kk < 2; ++kk) {
      bs8 af[2], wf[4];
#pragma unroll
      for (int m = 0; m < 2; ++m) {
        const int row = wm + m * 16 + lr;
        af[m] = *(const bs8*)&ash[(row << 3) | ((kk * 4 + lk) ^ (row & 7))];
      }
#pragma unroll
      for (int n = 0; n < 4; ++n) {
        const int row = wn + n * 16 + lr;
        wf[n] = *(const bs8*)&wsh[(row << 3) | ((kk * 4 + lk) ^ (row & 7))];
      }
#pragma unroll
      for (int m = 0; m < 2; ++m)
#pragma unroll
        for (int n = 0; n < 4; ++n)
          acc[m][n] = __builtin_amdgcn_mfma_f32_16x16x32_bf16(af[m], wf[n],
                                                              acc[m][n], 0, 0, 0);
    }
  }
  __syncthreads();  // GEMM LDS dead; reuse as KnT/VT

  const float* bias = kvsel ? bv : bk;
  if (kvsel == 0) {
#pragma unroll
    for (int m = 0; m < 2; ++m)
#pragma unroll
      for (int j = 0; j < 4; ++j)
#pragma unroll
        for (int hh = 0; hh < 2; ++hh) {
          const int c0 = wn + (2 * hh) * 16 + lr;
          const float p0 = __expf(acc[m][2 * hh][j] + bias[c0]);
          const float p1 = __expf(acc[m][2 * hh + 1][j] + bias[c0 + 16]);
          float s = p0 + p1;
#pragma unroll
          for (int o = 8; o >= 1; o >>= 1) s += __shfl_xor(s, o);
          const float inv = 1.0f / s;
          acc[m][2 * hh][j] = p0 * inv;
          acc[m][2 * hh + 1][j] = p1 * inv;
        }
  }
  {
    u16* T = kvsel ? VT : KnT;
#pragma unroll
    for (int m = 0; m < 2; ++m) {
      const int rb = wm + m * 16 + lk * 4;
#pragma unroll
      for (int n = 0; n < 4; ++n) {
        const int col = wn + n * 16 + lr;
        float v0 = acc[m][n][0], v1 = acc[m][n][1];
        float v2 = acc[m][n][2], v3 = acc[m][n][3];
        if (kvsel) {
          const float bb = bias[col];
          v0 += bb; v1 += bb; v2 += bb; v3 += bb;
        }
        uint2 w;
        w.x = pack2(v0, v1); w.y = pack2(v2, v3);
        *(uint2*)(T + col * 72 + rb) = w;
      }
    }
  }
  __syncthreads();

  if (kvsel == 0) {  // stats: wave w3 = head h
    const int h = w3;
    f32x16 aT, aK;
#pragma unroll
    for (int r = 0; r < 16; ++r) { aT[r] = 0.f; aK[r] = 0.f; }
    bs8 ones;
#pragma unroll
    for (int e = 0; e < 8; ++e) ones[e] = (short)0x3F80;
    const u16* kcol = KnT + (h * 32 + (lane & 31)) * 72;
    const u16* vcol = VT  + (h * 32 + (lane & 31)) * 72;
    const int hi8 = (lane >> 5) * 8;
#pragma unroll
    for (int ks = 0; ks < 4; ++ks) {
      const bs8 a  = *(const bs8*)(kcol + ks * 16 + hi8);
      const bs8 vb = *(const bs8*)(vcol + ks * 16 + hi8);
      aT = __builtin_amdgcn_mfma_f32_32x32x16_bf16(vb, a, aT, 0, 0, 0);  // tmpT
      aK = __builtin_amdgcn_mfma_f32_32x32x16_bf16(a, ones, aK, 0, 0, 0);
    }
    const long blk = (long)fb * gridDim.x + ch;
    float* po = ptm + blk * 8192 + h * 1024;
#pragma unroll
    for (int r = 0; r < 16; ++r) {
      const int dv = (r & 3) + 8 * (r >> 2) + 4 * (lane >> 5);
      po[dv * 32 + (lane & 31)] = aT[r];   // tmpT[h][dv][dk]
    }
    if ((lane & 31) == 0) {
#pragma unroll
      for (int r = 0; r < 16; ++r) {
        const int dk = (r & 3) + 8 * (r >> 2) + 4 * (lane >> 5);
        pks[blk * 256 + h * 32 + dk] = aK[r];
      }
    }
  }
}

// deterministic reduce of the 128 chunk-partials per fb (blockIdx.y)
__global__ void reduceStats(const float* __restrict__ pk,
                            const float* __restrict__ pt,
                            float* __restrict__ ksum, float* __restrict__ tmp) {
  const int b = blockIdx.y;
  const int i = blockIdx.x * 256 + threadIdx.x;  // 0..8447
  float s = 0.f;
  if (i < 256) {
    const float* p = pk + (long)b * 128 * 256 + i;
    for (int c = 0; c < 128; ++c) s += p[c * 256];
    ksum[(long)b * 256 + i] = s;
  } else {
    const int j = i - 256;
    const float* p = pt + (long)b * 128 * 8192 + j;
    for (int c = 0; c < 128; ++c) s += p[c * 8192];
    tmp[(long)b * 8192 + j] = s;
  }
}

// ---------------------------------------------------------------------------
// mixk (shfl-free): out = q + (1/F) sum_f alpha_f * (q @ tmp_f)
// ---------------------------------------------------------------------------
template <int F>
__global__ __launch_bounds__(256, 2) void mixk(const u16* __restrict__ q,
                                               const float* __restrict__ ksum,
                                               const float* __restrict__ tmp,
                                               u16* __restrict__ out) {
  constexpr int LF = (F == 2) ? 1 : 0;
  constexpr int QS = 264;               // u16 row stride (528 B, 16B-aligned)
  __shared__ u16 qsh[64 * QS];
  __shared__ float alsh[64][17];
  __shared__ float ksh[8][F * 36];      // padded per-head ksum
  const int t = threadIdx.x;
  const int h = t >> 5, dv = t & 31;
  const int b = blockIdx.y;
  const long row0 = (long)b * 8192 + (long)blockIdx.x * 64;

#pragma unroll
  for (int it = 0; it < 8; ++it) {
    const int i = t + it * 256;
    const int r = i >> 5, c = i & 31;
    *(int4*)&qsh[r * QS + c * 8] = *(const int4*)&q[(row0 + r) * 256 + c * 8];
  }
#pragma unroll
  for (int f = 0; f < F; ++f)
    ksh[h][f * 36 + dv] = ksum[((long)f * 4 + b) * 256 + t];
  float tr[F][32];
#pragma unroll
  for (int f = 0; f < F; ++f) {
    const float* tp = tmp + ((long)f * 4 + b) * 8192 + h * 1024 + dv * 32;
#pragma unroll
    for (int c = 0; c < 8; ++c) {
      const float4 v = *(const float4*)(tp + c * 4);
      tr[f][c * 4] = v.x; tr[f][c * 4 + 1] = v.y;
      tr[f][c * 4 + 2] = v.z; tr[f][c * 4 + 3] = v.w;
    }
  }
  __syncthreads();

  for (int d = t; d < 64 * 8 * F; d += 256) {
    const int f = d & (F - 1);
    const int hh = (d >> LF) & 7;
    const int r = d >> (3 + LF);
    const u16* qp = &qsh[r * QS + hh * 32];
    const float* kp = &ksh[hh][f * 36];
    float s = 0.f;
#pragma unroll
    for (int c = 0; c < 4; ++c) {
      const bs8 qa = *(const bs8*)(qp + c * 8);
#pragma unroll
      for (int j = 0; j < 8; ++j) s += bf2f((u16)qa[j]) * kp[c * 8 + j];
    }
    alsh[r][(hh << LF) | f] = 1.0f / s;
  }
  __syncthreads();

#pragma unroll 2
  for (int r = 0; r < 64; ++r) {
    float qr[32];
    const u16* qp = &qsh[r * QS + h * 32];
#pragma unroll
    for (int c = 0; c < 4; ++c) {
      const bs8 qa = *(const bs8*)(qp + c * 8);
#pragma unroll
      for (int j = 0; j < 8; ++j) qr[c * 8 + j] = bf2f((u16)qa[j]);
    }
    float acc = 0.f;
#pragma unroll
    for (int f = 0; f < F; ++f) {
      float s0 = 0.f, s1 = 0.f;
#pragma unroll
      for (int dk = 0; dk < 32; dk += 2) {
        s0 += qr[dk] * tr[f][dk];
        s1 += qr[dk + 1] * tr[f][dk + 1];
      }
      acc += (s0 + s1) * alsh[r][(h << LF) | f];
    }
    const float qv = bf2f(qsh[r * QS + t]);
    out[(row0 + r) * 256 + t] = f2bf(qv + acc * (1.0f / (float)F));
  }
}

// pre-convert the 10 attention (256x256) weight matrices to bf16 (row-major)
struct WTab10 { const float* p[10]; };
__global__ void convW(WTab10 tab, u16* __restrict__ dst) {
  const int s = blockIdx.y;
  const long i = ((long)blockIdx.x * 256 + threadIdx.x) * 4;
  const float4 v = *(const float4*)(tab.p[s] + i);
  ushort4 o;
  o.x = f2bf(v.x); o.y = f2bf(v.y); o.z = f2bf(v.z); o.w = f2bf(v.w);
  *(ushort4*)(dst + (long)s * 65536 + i) = o;
}

// pre-convert 26 matrices (24 FFN + ca_Wo + sa_Wo) to N-group-contiguous
// fragment order: WX[s][ng(16)][kt(8)][lane(64)][8],
//   row = ng*16 + (lane&15), col = kt*32 + (lane>>4)*8 + j
struct WTab26 { const float* p[26]; };
__global__ void convWX(WTab26 tab, u16* __restrict__ dst) {
  const int s = blockIdx.y;
  const int o8 = blockIdx.x * 256 + threadIdx.x;   // int4 index 0..8191
  const int lane = o8 & 63;
  const int kt = (o8 >> 6) & 7;
  const int ng = o8 >> 9;
  const int row = ng * 16 + (lane & 15);
  const int col = kt * 32 + (lane >> 4) * 8;
  const float* src = tab.p[s] + row * 256 + col;
  const float4 a = *(const float4*)src;
  const float4 b = *(const float4*)(src + 4);
  int4 val;
  val.x = pack2(a.x, a.y); val.y = pack2(a.z, a.w);
  val.z = pack2(b.x, b.y); val.w = pack2(b.z, b.w);
  *(int4*)(dst + (long)s * 65536 + (long)o8 * 8) = val;
}

// ---------------------------------------------------------------------------
extern "C" void kernel_launch(void* const* d_in, const int* in_sizes, int n_in,
                              void* d_out, int out_size, void* d_ws, size_t ws_size,
                              hipStream_t stream) {
  (void)in_sizes; (void)n_in; (void)out_size; (void)ws_size;
  const float* scores = (const float*)d_in[0];
  const float* query  = (const float*)d_in[1];
  const float* IF     = (const float*)d_in[2];
  const float* ca_Wq = (const float*)d_in[3];  const float* ca_bq = (const float*)d_in[4];
  const float* ca_Wk = (const float*)d_in[5];  const float* ca_bk = (const float*)d_in[6];
  const float* ca_Wv = (const float*)d_in[7];  const float* ca_bv = (const float*)d_in[8];
  const float* ca_Wo = (const float*)d_in[9];  const float* ca_bo = (const float*)d_in[10];
  const float* sa_Wq = (const float*)d_in[11]; const float* sa_bq = (const float*)d_in[12];
  const float* sa_Wk = (const float*)d_in[13]; const float* sa_bk = (const float*)d_in[14];
  const float* sa_Wv = (const float*)d_in[15]; const float* sa_bv = (const float*)d_in[16];
  const float* sa_Wo = (const float*)d_in[17]; const float* sa_bo = (const float*)d_in[18];
  const float* f1W1 = (const float*)d_in[19]; const float* f1b1 = (const float*)d_in[20];
  const float* f1W2 = (const float*)d_in[21]; const float* f1b2 = (const float*)d_in[22];
  const float* f1W3 = (const float*)d_in[23]; const float* f1b3 = (const float*)d_in[24];
  const float* f2W1 = (const float*)d_in[25]; const float* f2b1 = (const float*)d_in[26];
  const float* f2W2 = (const float*)d_in[27]; const float* f2b2 = (const float*)d_in[28];
  const float* f2W3 = (const float*)d_in[29]; const float* f2b3 = (const float*)d_in[30];

  char* ws = (char*)d_ws;
  u16* X0 = (u16*)(ws);                   // (M,256) bf16
  u16* X1 = (u16*)(ws + 16777216);        // mix output (also ptmBig region)
  float* ptmBig = (float*)(ws + 16777216);// kvstats partials (<=33.5MB)
  u16* W16 = (u16*)(ws + 67108864);       // 10 * 65536 bf16
  u16* WX  = (u16*)(ws + 68419584);       // 26 * 65536 bf16 = 3.4 MB
  float* ksum = (float*)(ws + 71827456);  // [8][256]
  float* tmpb = (float*)(ws + 71835648);  // [8][8192]
  float* pks  = (float*)(ws + 72097792);  // [8][128][256] = 1 MB
  float* qacc = (float*)d_out;            // fp32 accumulator = output

  WTab10 tab;
  tab.p[0] = ca_Wq; tab.p[1] = ca_Wk; tab.p[2] = ca_Wk + 65536;
  tab.p[3] = ca_Wv; tab.p[4] = ca_Wv + 65536; tab.p[5] = ca_Wo;
  tab.p[6] = sa_Wq; tab.p[7] = sa_Wk; tab.p[8] = sa_Wv; tab.p[9] = sa_Wo;
  convW<<<dim3(64, 10), 256, 0, stream>>>(tab, W16);

  WTab26 tabx;
  for (int e = 0; e < 4; ++e) {
    tabx.p[0 + e]  = f1W1 + e * 65536;
    tabx.p[4 + e]  = f1W2 + e * 65536;
    tabx.p[8 + e]  = f1W3 + e * 65536;
    tabx.p[12 + e] = f2W1 + e * 65536;
    tabx.p[16 + e] = f2W2 + e * 65536;
    tabx.p[20 + e] = f2W3 + e * 65536;
  }
  tabx.p[24] = ca_Wo;
  tabx.p[25] = sa_Wo;
  convWX<<<dim3(32, 26), 256, 0, stream>>>(tabx, WX);

  const dim3 gg(512, 2), gb(256);
  // ---- cross attention ----
  gemm256<true, EPI_QSM><<<gg, gb, 0, stream>>>(query, W16 + 0 * 65536L, ca_bq, X0);
  kvstats<<<dim3(128, 8), 1024, 0, stream>>>(
      IF, IF + 8388608L,
      W16 + 1 * 65536L, W16 + 2 * 65536L, W16 + 3 * 65536L, W16 + 4 * 65536L,
      ca_bk, ca_bk + 256, ca_bv, ca_bv + 256, pks, ptmBig);
  reduceStats<<<dim3(33, 8), 256, 0, stream>>>(pks, ptmBig, ksum, tmpb);
  mixk<2><<<dim3(128, 4), 256, 0, stream>>>(X0, ksum, tmpb, X1);
  ffn4<<<512, 1024, 0, stream>>>(X1, WX, 24, 0, ca_bo,
                                 f1b1, f1b2, f1b3, scores, query, qacc);
  // ---- self attention ----
  gemm256<true, EPI_QSM><<<gg, gb, 0, stream>>>(qacc, W16 + 6 * 65536L, sa_bq, X0);
  kvstats<<<dim3(128, 4), 1024, 0, stream>>>(
      qacc, qacc,
      W16 + 7 * 65536L, W16 + 7 * 65536L, W16 + 8 * 65536L, W16 + 8 * 65536L,
      sa_bk, sa_bk, sa_bv, sa_bv, pks, ptmBig);
  reduceStats<<<dim3(33, 4), 256, 0, stream>>>(pks, ptmBig, ksum, tmpb);
  mixk<1><<<dim3(128, 4), 256, 0, stream>>>(X0, ksum, tmpb, X1);
  ffn4<<<512, 1024, 0, stream>>>(X1, WX, 25, 12, sa_bo,
                                 f2b1, f2b2, f2b3, scores, qacc, qacc);
}

// Round 17
// 376.136 us; speedup vs baseline: 1.1424x; 1.1424x over previous
//
#include <hip/hip_runtime.h>

// ---------------------------------------------------------------------------
// HeterogeneousNormalizedAttentionBlock on MI355X (gfx950)
// B=4, LQ=LK=8192, E=256, H=8, D=32, NF=2, NE=4, HID=256;  M = B*LQ = 32768
// ---------------------------------------------------------------------------

typedef unsigned short u16;
typedef __attribute__((ext_vector_type(8))) short   bs8;    // 8 x bf16
typedef __attribute__((ext_vector_type(4))) float   f32x4;
typedef __attribute__((ext_vector_type(16))) float  f32x16;

__device__ __forceinline__ float bf2f(u16 u) {
  union { float f; unsigned i; } c; c.i = ((unsigned)u) << 16; return c.f;
}
__device__ __forceinline__ u16 f2bf(float f) {
  union { float f; unsigned i; } c; c.f = f;
  unsigned x = c.i;
  return (u16)((x + 0x7fffu + ((x >> 16) & 1u)) >> 16);   // RNE
}
__device__ __forceinline__ unsigned pack2(float a, float b) {
  return (unsigned)f2bf(a) | ((unsigned)f2bf(b) << 16);
}
__device__ __forceinline__ float gelu_f(float x) {
  const float t = x * (0.7978845608f + 0.0356774081f * x * x);
  return x * __builtin_amdgcn_rcpf(1.f + __expf(-2.f * t));
}

#define EPI_PLAIN 0
#define EPI_QSM   4   // feature-dim softmax over 32-col head groups

// ---------------------------------------------------------------------------
// Attention-side GEMM: C(M,256) = epi(A(M,256) @ W(256,256)^T + bias)
// BM=64, BN=128, BK=64, 4 waves (2x2), wave 32x64.  Grid (512,2), 4 blk/CU.
// ---------------------------------------------------------------------------
template <bool AF32, int EPI>
__global__ __launch_bounds__(256, 4) void gemm256(
    const void* __restrict__ Ain, const u16* __restrict__ W,
    const float* __restrict__ bias, u16* __restrict__ outb) {
  __shared__ int4 ash[512];    // 64 x 64 bf16, swizzled
  __shared__ int4 wsh[1024];   // 128 x 64 bf16, swizzled
  const int tid = threadIdx.x;
  const int m0 = blockIdx.x * 64, n0 = blockIdx.y * 128;
  const int wave = tid >> 6, lane = tid & 63;
  const int wm = (wave >> 1) * 32, wn = (wave & 1) * 64;
  const int lr = lane & 15, lk = lane >> 4;
  f32x4 acc[2][4];
#pragma unroll
  for (int m = 0; m < 2; ++m)
#pragma unroll
    for (int n = 0; n < 4; ++n) acc[m][n] = f32x4{0.f, 0.f, 0.f, 0.f};

  const float* Af = (const float*)Ain;
  const u16*   Ab = (const u16*)Ain;

  for (int kt = 0; kt < 4; ++kt) {
    const int k0 = kt * 64;
    if (kt) __syncthreads();
#pragma unroll
    for (int it = 0; it < 2; ++it) {   // A tile 64x64
      const int s = tid + it * 256;
      const int row = s >> 3, c16 = s & 7;
      const int dst = (row << 3) | (c16 ^ (row & 7));
      const long src = (long)(m0 + row) * 256 + k0 + c16 * 8;
      int4 val;
      if constexpr (AF32) {
        const float4* p = (const float4*)(Af + src);
        const float4 x = p[0], y = p[1];
        val.x = pack2(x.x, x.y); val.y = pack2(x.z, x.w);
        val.z = pack2(y.x, y.y); val.w = pack2(y.z, y.w);
      } else {
        val = *(const int4*)(Ab + src);
      }
      ash[dst] = val;
    }
#pragma unroll
    for (int it = 0; it < 4; ++it) {   // W tile 128x64
      const int s = tid + it * 256;
      const int row = s >> 3, c16 = s & 7;
      const int dst = (row << 3) | (c16 ^ (row & 7));
      wsh[dst] = *(const int4*)(W + (long)(n0 + row) * 256 + k0 + c16 * 8);
    }
    __syncthreads();
#pragma unroll
    for (int kk = 0; kk < 2; ++kk) {
      bs8 af[2], wf[4];
#pragma unroll
      for (int m = 0; m < 2; ++m) {
        const int row = wm + m * 16 + lr;
        af[m] = *(const bs8*)&ash[(row << 3) | ((kk * 4 + lk) ^ (row & 7))];
      }
#pragma unroll
      for (int n = 0; n < 4; ++n) {
        const int row = wn + n * 16 + lr;
        wf[n] = *(const bs8*)&wsh[(row << 3) | ((kk * 4 + lk) ^ (row & 7))];
      }
#pragma unroll
      for (int m = 0; m < 2; ++m)
#pragma unroll
        for (int n = 0; n < 4; ++n)
          acc[m][n] = __builtin_amdgcn_mfma_f32_16x16x32_bf16(af[m], wf[n],
                                                              acc[m][n], 0, 0, 0);
    }
  }
  // ---- epilogue ----
  if constexpr (EPI == EPI_QSM) {
#pragma unroll
    for (int m = 0; m < 2; ++m) {
      const int rb = m0 + wm + m * 16 + lk * 4;
#pragma unroll
      for (int j = 0; j < 4; ++j) {
#pragma unroll
        for (int hh = 0; hh < 2; ++hh) {
          const int c0 = n0 + wn + (2 * hh) * 16 + lr;
          const float p0 = __expf(acc[m][2 * hh][j] + bias[c0]);
          const float p1 = __expf(acc[m][2 * hh + 1][j] + bias[c0 + 16]);
          float s = p0 + p1;
#pragma unroll
          for (int o = 8; o >= 1; o >>= 1) s += __shfl_xor(s, o);
          const float inv = 1.0f / s;
          outb[(long)(rb + j) * 256 + c0]      = f2bf(p0 * inv);
          outb[(long)(rb + j) * 256 + c0 + 16] = f2bf(p1 * inv);
        }
      }
    }
  } else {
#pragma unroll
    for (int m = 0; m < 2; ++m) {
      const int rb = m0 + wm + m * 16 + lk * 4;
#pragma unroll
      for (int n = 0; n < 4; ++n) {
        const int gc = n0 + wn + n * 16 + lr;
        const float bv = bias[gc];
#pragma unroll
        for (int j = 0; j < 4; ++j)
          outb[(long)(rb + j) * 256 + gc] = f2bf(acc[m][n][j] + bv);
      }
    }
  }
}

// ---------------------------------------------------------------------------
// ffn4 (round-15 structure + Wo-proj fusion): {proj, 4-expert FFN, combine,
// residual}.  BM=64 (grid 512), 16 waves (2M x 8N, wave 32x32), BK=32.
// Proj layer: xsh = Xin @ Wo^T + bP (Xin staged in hsh), then expert loop.
// W from wave-contiguous WX[s][wn8(8)][kt(8)][n(2)][lane][8]; wf register
// double-buffer; setprio around MFMA (T5).  xsh+hsh = 64KB, 2 blocks/CU.
// ---------------------------------------------------------------------------
__global__ __launch_bounds__(1024, 4) void ffn4(
    const u16* __restrict__ Xin, const u16* __restrict__ WX,
    int wPslot, int wbase, const float* __restrict__ bP,
    const float* __restrict__ b1, const float* __restrict__ b2,
    const float* __restrict__ b3, const float* __restrict__ scores,
    const float* __restrict__ csrc, float* __restrict__ outf) {
  __shared__ int4 xsh[2048];   // 32KB: x (proj output) 64x256, chunk-XOR8
  __shared__ int4 hsh[2048];   // 32KB: Xin staging, then h (in-place)
  const int tid = threadIdx.x, wave = tid >> 6, lane = tid & 63;
  const int wm = (wave >> 3) * 32;   // 0 or 32
  const int wn8 = wave & 7;          // N-group: cols wn8*32 .. wn8*32+31
  const int lr = lane & 15, lk = lane >> 4;
  const long m0 = (long)blockIdx.x * 64;

  // stage Xin (64 x 256 bf16) into hsh
#pragma unroll
  for (int it = 0; it < 2; ++it) {
    const int s = tid + it * 1024;
    const int row = s >> 5, c8 = s & 31;
    const int cs = (c8 & 24) | ((c8 ^ row) & 7);
    hsh[row * 32 + cs] = *(const int4*)(Xin + (m0 + row) * 256 + c8 * 8);
  }
  __syncthreads();

  f32x4 acc[2][2];

  // ---- proj layer: x = Xin @ Wo^T + bP -> xsh (no gelu) ----
  {
    const u16* wp = WX + (((long)wPslot) << 16) + (wn8 << 13) + lane * 8;
#pragma unroll
    for (int m = 0; m < 2; ++m)
#pragma unroll
      for (int n = 0; n < 2; ++n) acc[m][n] = f32x4{0.f, 0.f, 0.f, 0.f};
    bs8 wf[2], wfn[2];
    wf[0] = *(const bs8*)(wp);
    wf[1] = *(const bs8*)(wp + 512);
#pragma unroll
    for (int kt = 0; kt < 8; ++kt) {
      if (kt < 7) {
        wfn[0] = *(const bs8*)(wp + (kt + 1) * 1024);
        wfn[1] = *(const bs8*)(wp + (kt + 1) * 1024 + 512);
      }
      bs8 af[2];
      const int c8 = kt * 4 + lk;
#pragma unroll
      for (int m = 0; m < 2; ++m) {
        const int row = wm + m * 16 + lr;
        const int cs = (c8 & 24) | ((c8 ^ row) & 7);
        af[m] = *(const bs8*)&hsh[row * 32 + cs];
      }
      __builtin_amdgcn_s_setprio(1);
#pragma unroll
      for (int m = 0; m < 2; ++m)
#pragma unroll
        for (int n = 0; n < 2; ++n)
          acc[m][n] = __builtin_amdgcn_mfma_f32_16x16x32_bf16(
              af[m], wf[n], acc[m][n], 0, 0, 0);
      __builtin_amdgcn_s_setprio(0);
      wf[0] = wfn[0]; wf[1] = wfn[1];
    }
    // write x to xsh (no hazard: xsh untouched so far)
    u16* xp = (u16*)xsh;
#pragma unroll
    for (int m = 0; m < 2; ++m)
#pragma unroll
      for (int n = 0; n < 2; ++n) {
        const int col = wn8 * 32 + n * 16 + lr;
        const float bv = bP[col];
        const int c8w = col >> 3;
#pragma unroll
        for (int j = 0; j < 4; ++j) {
          const int row = wm + m * 16 + lk * 4 + j;
          const int cs = (c8w & 24) | ((c8w ^ row) & 7);
          xp[row * 256 + cs * 8 + (col & 7)] = f2bf(acc[m][n][j] + bv);
        }
      }
    __syncthreads();   // xsh visible to all waves
  }

  f32x4 oacc[2][2];
#pragma unroll
  for (int m = 0; m < 2; ++m)
#pragma unroll
    for (int n = 0; n < 2; ++n) oacc[m][n] = f32x4{0.f, 0.f, 0.f, 0.f};

  for (int e = 0; e < 4; ++e) {
#pragma unroll 1
    for (int l = 0; l < 3; ++l) {
      const u16* wp = WX + (((long)(wbase + l * 4 + e)) << 16) +
                      (wn8 << 13) + lane * 8;
      const int4* asrc = (l == 0) ? xsh : hsh;
#pragma unroll
      for (int m = 0; m < 2; ++m)
#pragma unroll
        for (int n = 0; n < 2; ++n) acc[m][n] = f32x4{0.f, 0.f, 0.f, 0.f};
      bs8 wf[2], wfn[2];
      wf[0] = *(const bs8*)(wp);
      wf[1] = *(const bs8*)(wp + 512);
#pragma unroll
      for (int kt = 0; kt < 8; ++kt) {
        if (kt < 7) {   // prefetch kt+1 fragments (covered by MFMA below)
          wfn[0] = *(const bs8*)(wp + (kt + 1) * 1024);
          wfn[1] = *(const bs8*)(wp + (kt + 1) * 1024 + 512);
        }
        bs8 af[2];
        const int c8 = kt * 4 + lk;
#pragma unroll
        for (int m = 0; m < 2; ++m) {
          const int row = wm + m * 16 + lr;
          const int cs = (c8 & 24) | ((c8 ^ row) & 7);
          af[m] = *(const bs8*)&asrc[row * 32 + cs];
        }
        __builtin_amdgcn_s_setprio(1);
#pragma unroll
        for (int m = 0; m < 2; ++m)
#pragma unroll
          for (int n = 0; n < 2; ++n)
            acc[m][n] = __builtin_amdgcn_mfma_f32_16x16x32_bf16(
                af[m], wf[n], acc[m][n], 0, 0, 0);
        __builtin_amdgcn_s_setprio(0);
        wf[0] = wfn[0]; wf[1] = wfn[1];
      }
      if (l < 2) {
        __syncthreads();   // all asrc reads done before hsh overwrite
        const float* bb = (l == 0 ? b1 : b2) + e * 256;
        u16* hp = (u16*)hsh;
#pragma unroll
        for (int m = 0; m < 2; ++m)
#pragma unroll
          for (int n = 0; n < 2; ++n) {
            const int col = wn8 * 32 + n * 16 + lr;
            const float bv = bb[col];
            const int c8w = col >> 3;
#pragma unroll
            for (int j = 0; j < 4; ++j) {
              const int row = wm + m * 16 + lk * 4 + j;
              const int cs = (c8w & 24) | ((c8w ^ row) & 7);
              hp[row * 256 + cs * 8 + (col & 7)] =
                  f2bf(gelu_f(acc[m][n][j] + bv));
            }
          }
        __syncthreads();   // hsh visible to next layer
      } else {  // + b3, score-weighted accumulate (registers only)
#pragma unroll
        for (int m = 0; m < 2; ++m) {
#pragma unroll
          for (int j = 0; j < 4; ++j) {
            const float sc = scores[(m0 + wm + m * 16 + lk * 4 + j) * 4 + e];
#pragma unroll
            for (int n = 0; n < 2; ++n)
              oacc[m][n][j] +=
                  sc * (acc[m][n][j] + b3[e * 256 + wn8 * 32 + n * 16 + lr]);
          }
        }
      }
    }
  }
#pragma unroll
  for (int m = 0; m < 2; ++m) {
#pragma unroll
    for (int n = 0; n < 2; ++n) {
      const int col = wn8 * 32 + n * 16 + lr;
#pragma unroll
      for (int j = 0; j < 4; ++j) {
        const long idx = (m0 + wm + m * 16 + lk * 4 + j) * 256 + col;
        outf[idx] = csrc[idx] + oacc[m][n][j];
      }
    }
  }
}

// ---------------------------------------------------------------------------
// kvstats (merged-f): fused {K-proj, V-proj, K-softmax, per-head stats}.
// blockIdx.y = fb = f*4 + b; per-f pointers passed explicitly.
// ---------------------------------------------------------------------------
__global__ __launch_bounds__(1024, 4) void kvstats(
    const float* __restrict__ A0, const float* __restrict__ A1,
    const u16* __restrict__ Wk0, const u16* __restrict__ Wk1,
    const u16* __restrict__ Wv0, const u16* __restrict__ Wv1,
    const float* __restrict__ bk0, const float* __restrict__ bk1,
    const float* __restrict__ bv0, const float* __restrict__ bv1,
    float* __restrict__ pks, float* __restrict__ ptm) {
  __shared__ __align__(16) char smem[73728];
  int4* ash  = (int4*)smem;        // 512 slots  (64x64 bf16)
  int4* wksh = ash + 512;          // 2048 slots (256x64)
  int4* wvsh = wksh + 2048;        // 2048 slots
  u16* KnT = (u16*)smem;           // [256][72] bf16 (transposed, padded)
  u16* VT  = KnT + 256 * 72;
  const int tid = threadIdx.x;
  const int wave = tid >> 6, lane = tid & 63;
  const int lr = lane & 15, lk = lane >> 4;
  const int kvsel = wave >> 3, w3 = wave & 7;
  const int wm = (w3 >> 2) * 32, wn = (w3 & 3) * 64;
  const int fb = blockIdx.y, ch = blockIdx.x;
  const int f = fb >> 2, b = fb & 3;
  const float* Ain = f ? A1 : A0;
  const u16* Wk = f ? Wk1 : Wk0;
  const u16* Wv = f ? Wv1 : Wv0;
  const float* bk = f ? bk1 : bk0;
  const float* bv = f ? bv1 : bv0;
  const long r0 = (long)b * 8192 + (long)ch * 64;

  f32x4 acc[2][4];
#pragma unroll
  for (int m = 0; m < 2; ++m)
#pragma unroll
    for (int n = 0; n < 4; ++n) acc[m][n] = f32x4{0.f, 0.f, 0.f, 0.f};

  for (int kt = 0; kt < 4; ++kt) {
    const int k0 = kt * 64;
    if (kt) __syncthreads();
    if (tid < 512) {  // A tile 64x64 fp32 -> bf16
      const int row = tid >> 3, c16 = tid & 7;
      const int dst = (row << 3) | (c16 ^ (row & 7));
      const float4* p = (const float4*)(Ain + (r0 + row) * 256 + k0 + c16 * 8);
      const float4 x = p[0], y = p[1];
      int4 val;
      val.x = pack2(x.x, x.y); val.y = pack2(x.z, x.w);
      val.z = pack2(y.x, y.y); val.w = pack2(y.z, y.w);
      ash[dst] = val;
    }
#pragma unroll
    for (int it = 0; it < 2; ++it) {  // Wk + Wv tiles 256x64
      const int s = tid + it * 1024;
      const int row = s >> 3, c16 = s & 7;
      const int dst = (row << 3) | (c16 ^ (row & 7));
      wksh[dst] = *(const int4*)(Wk + (long)row * 256 + k0 + c16 * 8);
      wvsh[dst] = *(const int4*)(Wv + (long)row * 256 + k0 + c16 * 8);
    }
    __syncthreads();
    const int4* wsh = kvsel ? wvsh : wksh;
#pragma unroll
    for (int kk = 0; kk < 2; ++kk) {
      bs8 af[2], wf[4];
#pragma unroll
      for (int m = 0; m < 2; ++m) {
        const int row = wm + m * 16 + lr;
        af[m] = *(const bs8*)&ash[(row << 3) | ((kk * 4 + lk) ^ (row & 7))];
      }
#pragma unroll
      for (int n = 0; n < 4; ++n) {
        const int row = wn + n * 16 + lr;
        wf[n] = *(const bs8*)&wsh[(row << 3) | ((kk * 4 + lk) ^ (row & 7))];
      }
#pragma unroll
      for (int m = 0; m < 2; ++m)
#pragma unroll
        for (int n = 0; n < 4; ++n)
          acc[m][n] = __builtin_amdgcn_mfma_f32_16x16x32_bf16(af[m], wf[n],
                                                              acc[m][n], 0, 0, 0);
    }
  }
  __syncthreads();  // GEMM LDS dead; reuse as KnT/VT

  const float* bias = kvsel ? bv : bk;
  if (kvsel == 0) {
#pragma unroll
    for (int m = 0; m < 2; ++m)
#pragma unroll
      for (int j = 0; j < 4; ++j)
#pragma unroll
        for (int hh = 0; hh < 2; ++hh) {
          const int c0 = wn + (2 * hh) * 16 + lr;
          const float p0 = __expf(acc[m][2 * hh][j] + bias[c0]);
          const float p1 = __expf(acc[m][2 * hh + 1][j] + bias[c0 + 16]);
          float s = p0 + p1;
#pragma unroll
          for (int o = 8; o >= 1; o >>= 1) s += __shfl_xor(s, o);
          const float inv = 1.0f / s;
          acc[m][2 * hh][j] = p0 * inv;
          acc[m][2 * hh + 1][j] = p1 * inv;
        }
  }
  {
    u16* T = kvsel ? VT : KnT;
#pragma unroll
    for (int m = 0; m < 2; ++m) {
      const int rb = wm + m * 16 + lk * 4;
#pragma unroll
      for (int n = 0; n < 4; ++n) {
        const int col = wn + n * 16 + lr;
        float v0 = acc[m][n][0], v1 = acc[m][n][1];
        float v2 = acc[m][n][2], v3 = acc[m][n][3];
        if (kvsel) {
          const float bb = bias[col];
          v0 += bb; v1 += bb; v2 += bb; v3 += bb;
        }
        uint2 w;
        w.x = pack2(v0, v1); w.y = pack2(v2, v3);
        *(uint2*)(T + col * 72 + rb) = w;
      }
    }
  }
  __syncthreads();

  if (kvsel == 0) {  // stats: wave w3 = head h
    const int h = w3;
    f32x16 aT, aK;
#pragma unroll
    for (int r = 0; r < 16; ++r) { aT[r] = 0.f; aK[r] = 0.f; }
    bs8 ones;
#pragma unroll
    for (int e = 0; e < 8; ++e) ones[e] = (short)0x3F80;
    const u16* kcol = KnT + (h * 32 + (lane & 31)) * 72;
    const u16* vcol = VT  + (h * 32 + (lane & 31)) * 72;
    const int hi8 = (lane >> 5) * 8;
#pragma unroll
    for (int ks = 0; ks < 4; ++ks) {
      const bs8 a  = *(const bs8*)(kcol + ks * 16 + hi8);
      const bs8 vb = *(const bs8*)(vcol + ks * 16 + hi8);
      aT = __builtin_amdgcn_mfma_f32_32x32x16_bf16(vb, a, aT, 0, 0, 0);  // tmpT
      aK = __builtin_amdgcn_mfma_f32_32x32x16_bf16(a, ones, aK, 0, 0, 0);
    }
    const long blk = (long)fb * gridDim.x + ch;
    float* po = ptm + blk * 8192 + h * 1024;
#pragma unroll
    for (int r = 0; r < 16; ++r) {
      const int dv = (r & 3) + 8 * (r >> 2) + 4 * (lane >> 5);
      po[dv * 32 + (lane & 31)] = aT[r];   // tmpT[h][dv][dk]
    }
    if ((lane & 31) == 0) {
#pragma unroll
      for (int r = 0; r < 16; ++r) {
        const int dk = (r & 3) + 8 * (r >> 2) + 4 * (lane >> 5);
        pks[blk * 256 + h * 32 + dk] = aK[r];
      }
    }
  }
}

// deterministic reduce of the 128 chunk-partials per fb (blockIdx.y)
__global__ void reduceStats(const float* __restrict__ pk,
                            const float* __restrict__ pt,
                            float* __restrict__ ksum, float* __restrict__ tmp) {
  const int b = blockIdx.y;
  const int i = blockIdx.x * 256 + threadIdx.x;  // 0..8447
  float s = 0.f;
  if (i < 256) {
    const float* p = pk + (long)b * 128 * 256 + i;
    for (int c = 0; c < 128; ++c) s += p[c * 256];
    ksum[(long)b * 256 + i] = s;
  } else {
    const int j = i - 256;
    const float* p = pt + (long)b * 128 * 8192 + j;
    for (int c = 0; c < 128; ++c) s += p[c * 8192];
    tmp[(long)b * 8192 + j] = s;
  }
}

// ---------------------------------------------------------------------------
// mixk (shfl-free): out = q + (1/F) sum_f alpha_f * (q @ tmp_f)
// ---------------------------------------------------------------------------
template <int F>
__global__ __launch_bounds__(256, 2) void mixk(const u16* __restrict__ q,
                                               const float* __restrict__ ksum,
                                               const float* __restrict__ tmp,
                                               u16* __restrict__ out) {
  constexpr int LF = (F == 2) ? 1 : 0;
  constexpr int QS = 264;               // u16 row stride (528 B, 16B-aligned)
  __shared__ u16 qsh[64 * QS];
  __shared__ float alsh[64][17];
  __shared__ float ksh[8][F * 36];      // padded per-head ksum
  const int t = threadIdx.x;
  const int h = t >> 5, dv = t & 31;
  const int b = blockIdx.y;
  const long row0 = (long)b * 8192 + (long)blockIdx.x * 64;

#pragma unroll
  for (int it = 0; it < 8; ++it) {
    const int i = t + it * 256;
    const int r = i >> 5, c = i & 31;
    *(int4*)&qsh[r * QS + c * 8] = *(const int4*)&q[(row0 + r) * 256 + c * 8];
  }
#pragma unroll
  for (int f = 0; f < F; ++f)
    ksh[h][f * 36 + dv] = ksum[((long)f * 4 + b) * 256 + t];
  float tr[F][32];
#pragma unroll
  for (int f = 0; f < F; ++f) {
    const float* tp = tmp + ((long)f * 4 + b) * 8192 + h * 1024 + dv * 32;
#pragma unroll
    for (int c = 0; c < 8; ++c) {
      const float4 v = *(const float4*)(tp + c * 4);
      tr[f][c * 4] = v.x; tr[f][c * 4 + 1] = v.y;
      tr[f][c * 4 + 2] = v.z; tr[f][c * 4 + 3] = v.w;
    }
  }
  __syncthreads();

  for (int d = t; d < 64 * 8 * F; d += 256) {
    const int f = d & (F - 1);
    const int hh = (d >> LF) & 7;
    const int r = d >> (3 + LF);
    const u16* qp = &qsh[r * QS + hh * 32];
    const float* kp = &ksh[hh][f * 36];
    float s = 0.f;
#pragma unroll
    for (int c = 0; c < 4; ++c) {
      const bs8 qa = *(const bs8*)(qp + c * 8);
#pragma unroll
      for (int j = 0; j < 8; ++j) s += bf2f((u16)qa[j]) * kp[c * 8 + j];
    }
    alsh[r][(hh << LF) | f] = 1.0f / s;
  }
  __syncthreads();

#pragma unroll 2
  for (int r = 0; r < 64; ++r) {
    float qr[32];
    const u16* qp = &qsh[r * QS + h * 32];
#pragma unroll
    for (int c = 0; c < 4; ++c) {
      const bs8 qa = *(const bs8*)(qp + c * 8);
#pragma unroll
      for (int j = 0; j < 8; ++j) qr[c * 8 + j] = bf2f((u16)qa[j]);
    }
    float acc = 0.f;
#pragma unroll
    for (int f = 0; f < F; ++f) {
      float s0 = 0.f, s1 = 0.f;
#pragma unroll
      for (int dk = 0; dk < 32; dk += 2) {
        s0 += qr[dk] * tr[f][dk];
        s1 += qr[dk + 1] * tr[f][dk + 1];
      }
      acc += (s0 + s1) * alsh[r][(h << LF) | f];
    }
    const float qv = bf2f(qsh[r * QS + t]);
    out[(row0 + r) * 256 + t] = f2bf(qv + acc * (1.0f / (float)F));
  }
}

// pre-convert the 10 attention (256x256) weight matrices to bf16 (row-major)
struct WTab10 { const float* p[10]; };
__global__ void convW(WTab10 tab, u16* __restrict__ dst) {
  const int s = blockIdx.y;
  const long i = ((long)blockIdx.x * 256 + threadIdx.x) * 4;
  const float4 v = *(const float4*)(tab.p[s] + i);
  ushort4 o;
  o.x = f2bf(v.x); o.y = f2bf(v.y); o.z = f2bf(v.z); o.w = f2bf(v.w);
  *(ushort4*)(dst + (long)s * 65536 + i) = o;
}

// pre-convert 26 matrices (24 FFN + ca_Wo + sa_Wo) to WAVE-CONTIGUOUS order:
// WX[s][wn8(8)][kt(8)][n(2)][lane(64)][8],
//   row = wn8*32 + n*16 + (lane&15), col = kt*32 + (lane>>4)*8 + j
struct WTab26 { const float* p[26]; };
__global__ void convWX(WTab26 tab, u16* __restrict__ dst) {
  const int s = blockIdx.y;
  const int o8 = blockIdx.x * 256 + threadIdx.x;   // 0..8191
  const int lane = o8 & 63;
  const int n = (o8 >> 6) & 1;
  const int kt = (o8 >> 7) & 7;
  const int wn8 = o8 >> 10;
  const int row = wn8 * 32 + n * 16 + (lane & 15);
  const int col = kt * 32 + (lane >> 4) * 8;
  const float* src = tab.p[s] + row * 256 + col;
  const float4 a = *(const float4*)src;
  const float4 b = *(const float4*)(src + 4);
  int4 val;
  val.x = pack2(a.x, a.y); val.y = pack2(a.z, a.w);
  val.z = pack2(b.x, b.y); val.w = pack2(b.z, b.w);
  *(int4*)(dst + (long)s * 65536 + (long)o8 * 8) = val;
}

// ---------------------------------------------------------------------------
extern "C" void kernel_launch(void* const* d_in, const int* in_sizes, int n_in,
                              void* d_out, int out_size, void* d_ws, size_t ws_size,
                              hipStream_t stream) {
  (void)in_sizes; (void)n_in; (void)out_size; (void)ws_size;
  const float* scores = (const float*)d_in[0];
  const float* query  = (const float*)d_in[1];
  const float* IF     = (const float*)d_in[2];
  const float* ca_Wq = (const float*)d_in[3];  const float* ca_bq = (const float*)d_in[4];
  const float* ca_Wk = (const float*)d_in[5];  const float* ca_bk = (const float*)d_in[6];
  const float* ca_Wv = (const float*)d_in[7];  const float* ca_bv = (const float*)d_in[8];
  const float* ca_Wo = (const float*)d_in[9];  const float* ca_bo = (const float*)d_in[10];
  const float* sa_Wq = (const float*)d_in[11]; const float* sa_bq = (const float*)d_in[12];
  const float* sa_Wk = (const float*)d_in[13]; const float* sa_bk = (const float*)d_in[14];
  const float* sa_Wv = (const float*)d_in[15]; const float* sa_bv = (const float*)d_in[16];
  const float* sa_Wo = (const float*)d_in[17]; const float* sa_bo = (const float*)d_in[18];
  const float* f1W1 = (const float*)d_in[19]; const float* f1b1 = (const float*)d_in[20];
  const float* f1W2 = (const float*)d_in[21]; const float* f1b2 = (const float*)d_in[22];
  const float* f1W3 = (const float*)d_in[23]; const float* f1b3 = (const float*)d_in[24];
  const float* f2W1 = (const float*)d_in[25]; const float* f2b1 = (const float*)d_in[26];
  const float* f2W2 = (const float*)d_in[27]; const float* f2b2 = (const float*)d_in[28];
  const float* f2W3 = (const float*)d_in[29]; const float* f2b3 = (const float*)d_in[30];

  char* ws = (char*)d_ws;
  u16* X0 = (u16*)(ws);                   // (M,256) bf16
  u16* X1 = (u16*)(ws + 16777216);        // mix output (also ptmBig region)
  float* ptmBig = (float*)(ws + 16777216);// kvstats partials (<=33.5MB)
  u16* W16 = (u16*)(ws + 67108864);       // 10 * 65536 bf16
  u16* WX  = (u16*)(ws + 68419584);       // 26 * 65536 bf16 = 3.4 MB
  float* ksum = (float*)(ws + 71827456);  // [8][256]
  float* tmpb = (float*)(ws + 71835648);  // [8][8192]
  float* pks  = (float*)(ws + 72097792);  // [8][128][256] = 1 MB
  float* qacc = (float*)d_out;            // fp32 accumulator = output

  WTab10 tab;
  tab.p[0] = ca_Wq; tab.p[1] = ca_Wk; tab.p[2] = ca_Wk + 65536;
  tab.p[3] = ca_Wv; tab.p[4] = ca_Wv + 65536; tab.p[5] = ca_Wo;
  tab.p[6] = sa_Wq; tab.p[7] = sa_Wk; tab.p[8] = sa_Wv; tab.p[9] = sa_Wo;
  convW<<<dim3(64, 10), 256, 0, stream>>>(tab, W16);

  WTab26 tabx;
  for (int e = 0; e < 4; ++e) {
    tabx.p[0 + e]  = f1W1 + e * 65536;
    tabx.p[4 + e]  = f1W2 + e * 65536;
    tabx.p[8 + e]  = f1W3 + e * 65536;
    tabx.p[12 + e] = f2W1 + e * 65536;
    tabx.p[16 + e] = f2W2 + e * 65536;
    tabx.p[20 + e] = f2W3 + e * 65536;
  }
  tabx.p[24] = ca_Wo;
  tabx.p[25] = sa_Wo;
  convWX<<<dim3(32, 26), 256, 0, stream>>>(tabx, WX);

  const dim3 gg(512, 2), gb(256);
  // ---- cross attention ----
  gemm256<true, EPI_QSM><<<gg, gb, 0, stream>>>(query, W16 + 0 * 65536L, ca_bq, X0);
  kvstats<<<dim3(128, 8), 1024, 0, stream>>>(
      IF, IF + 8388608L,
      W16 + 1 * 65536L, W16 + 2 * 65536L, W16 + 3 * 65536L, W16 + 4 * 65536L,
      ca_bk, ca_bk + 256, ca_bv, ca_bv + 256, pks, ptmBig);
  reduceStats<<<dim3(33, 8), 256, 0, stream>>>(pks, ptmBig, ksum, tmpb);
  mixk<2><<<dim3(128, 4), 256, 0, stream>>>(X0, ksum, tmpb, X1);
  ffn4<<<512, 1024, 0, stream>>>(X1, WX, 24, 0, ca_bo,
                                 f1b1, f1b2, f1b3, scores, query, qacc);
  // ---- self attention ----
  gemm256<true, EPI_QSM><<<gg, gb, 0, stream>>>(qacc, W16 + 6 * 65536L, sa_bq, X0);
  kvstats<<<dim3(128, 4), 1024, 0, stream>>>(
      qacc, qacc,
      W16 + 7 * 65536L, W16 + 7 * 65536L, W16 + 8 * 65536L, W16 + 8 * 65536L,
      sa_bk, sa_bk, sa_bv, sa_bv, pks, ptmBig);
  reduceStats<<<dim3(33, 4), 256, 0, stream>>>(pks, ptmBig, ksum, tmpb);
  mixk<1><<<dim3(128, 4), 256, 0, stream>>>(X0, ksum, tmpb, X1);
  ffn4<<<512, 1024, 0, stream>>>(X1, WX, 25, 12, sa_bo,
                                 f2b1, f2b2, f2b3, scores, qacc, qacc);
}

// Round 18
// 371.405 us; speedup vs baseline: 1.1570x; 1.0127x over previous
//
#include <hip/hip_runtime.h>

// ---------------------------------------------------------------------------
// HeterogeneousNormalizedAttentionBlock on MI355X (gfx950)
// B=4, LQ=LK=8192, E=256, H=8, D=32, NF=2, NE=4, HID=256;  M = B*LQ = 32768
// ---------------------------------------------------------------------------

typedef unsigned short u16;
typedef __attribute__((ext_vector_type(8))) short   bs8;    // 8 x bf16
typedef __attribute__((ext_vector_type(4))) float   f32x4;
typedef __attribute__((ext_vector_type(16))) float  f32x16;

__device__ __forceinline__ float bf2f(u16 u) {
  union { float f; unsigned i; } c; c.i = ((unsigned)u) << 16; return c.f;
}
__device__ __forceinline__ u16 f2bf(float f) {
  union { float f; unsigned i; } c; c.f = f;
  unsigned x = c.i;
  return (u16)((x + 0x7fffu + ((x >> 16) & 1u)) >> 16);   // RNE
}
__device__ __forceinline__ unsigned pack2(float a, float b) {
  return (unsigned)f2bf(a) | ((unsigned)f2bf(b) << 16);
}
__device__ __forceinline__ float gelu_f(float x) {
  const float t = x * (0.7978845608f + 0.0356774081f * x * x);
  return x * __builtin_amdgcn_rcpf(1.f + __expf(-2.f * t));
}

#define EPI_PLAIN 0
#define EPI_QSM   4   // feature-dim softmax over 32-col head groups

// ---------------------------------------------------------------------------
// Attention-side GEMM: C(M,256) = epi(A(M,256) @ W(256,256)^T + bias)
// BM=64, BN=128, BK=64, 4 waves (2x2), wave 32x64.  Grid (512,2), 4 blk/CU.
// ---------------------------------------------------------------------------
template <bool AF32, int EPI>
__global__ __launch_bounds__(256, 4) void gemm256(
    const void* __restrict__ Ain, const u16* __restrict__ W,
    const float* __restrict__ bias, u16* __restrict__ outb) {
  __shared__ int4 ash[512];    // 64 x 64 bf16, swizzled
  __shared__ int4 wsh[1024];   // 128 x 64 bf16, swizzled
  const int tid = threadIdx.x;
  const int m0 = blockIdx.x * 64, n0 = blockIdx.y * 128;
  const int wave = tid >> 6, lane = tid & 63;
  const int wm = (wave >> 1) * 32, wn = (wave & 1) * 64;
  const int lr = lane & 15, lk = lane >> 4;
  f32x4 acc[2][4];
#pragma unroll
  for (int m = 0; m < 2; ++m)
#pragma unroll
    for (int n = 0; n < 4; ++n) acc[m][n] = f32x4{0.f, 0.f, 0.f, 0.f};

  const float* Af = (const float*)Ain;
  const u16*   Ab = (const u16*)Ain;

  for (int kt = 0; kt < 4; ++kt) {
    const int k0 = kt * 64;
    if (kt) __syncthreads();
#pragma unroll
    for (int it = 0; it < 2; ++it) {   // A tile 64x64
      const int s = tid + it * 256;
      const int row = s >> 3, c16 = s & 7;
      const int dst = (row << 3) | (c16 ^ (row & 7));
      const long src = (long)(m0 + row) * 256 + k0 + c16 * 8;
      int4 val;
      if constexpr (AF32) {
        const float4* p = (const float4*)(Af + src);
        const float4 x = p[0], y = p[1];
        val.x = pack2(x.x, x.y); val.y = pack2(x.z, x.w);
        val.z = pack2(y.x, y.y); val.w = pack2(y.z, y.w);
      } else {
        val = *(const int4*)(Ab + src);
      }
      ash[dst] = val;
    }
#pragma unroll
    for (int it = 0; it < 4; ++it) {   // W tile 128x64
      const int s = tid + it * 256;
      const int row = s >> 3, c16 = s & 7;
      const int dst = (row << 3) | (c16 ^ (row & 7));
      wsh[dst] = *(const int4*)(W + (long)(n0 + row) * 256 + k0 + c16 * 8);
    }
    __syncthreads();
#pragma unroll
    for (int kk = 0; kk < 2; ++kk) {
      bs8 af[2], wf[4];
#pragma unroll
      for (int m = 0; m < 2; ++m) {
        const int row = wm + m * 16 + lr;
        af[m] = *(const bs8*)&ash[(row << 3) | ((kk * 4 + lk) ^ (row & 7))];
      }
#pragma unroll
      for (int n = 0; n < 4; ++n) {
        const int row = wn + n * 16 + lr;
        wf[n] = *(const bs8*)&wsh[(row << 3) | ((kk * 4 + lk) ^ (row & 7))];
      }
#pragma unroll
      for (int m = 0; m < 2; ++m)
#pragma unroll
        for (int n = 0; n < 4; ++n)
          acc[m][n] = __builtin_amdgcn_mfma_f32_16x16x32_bf16(af[m], wf[n],
                                                              acc[m][n], 0, 0, 0);
    }
  }
  // ---- epilogue ----
  if constexpr (EPI == EPI_QSM) {
#pragma unroll
    for (int m = 0; m < 2; ++m) {
      const int rb = m0 + wm + m * 16 + lk * 4;
#pragma unroll
      for (int j = 0; j < 4; ++j) {
#pragma unroll
        for (int hh = 0; hh < 2; ++hh) {
          const int c0 = n0 + wn + (2 * hh) * 16 + lr;
          const float p0 = __expf(acc[m][2 * hh][j] + bias[c0]);
          const float p1 = __expf(acc[m][2 * hh + 1][j] + bias[c0 + 16]);
          float s = p0 + p1;
#pragma unroll
          for (int o = 8; o >= 1; o >>= 1) s += __shfl_xor(s, o);
          const float inv = 1.0f / s;
          outb[(long)(rb + j) * 256 + c0]      = f2bf(p0 * inv);
          outb[(long)(rb + j) * 256 + c0 + 16] = f2bf(p1 * inv);
        }
      }
    }
  } else {
#pragma unroll
    for (int m = 0; m < 2; ++m) {
      const int rb = m0 + wm + m * 16 + lk * 4;
#pragma unroll
      for (int n = 0; n < 4; ++n) {
        const int gc = n0 + wn + n * 16 + lr;
        const float bv = bias[gc];
#pragma unroll
        for (int j = 0; j < 4; ++j)
          outb[(long)(rb + j) * 256 + gc] = f2bf(acc[m][n][j] + bv);
      }
    }
  }
}

// ---------------------------------------------------------------------------
// ffn4 (round-17 proven, 117.5us): {Wo proj, 4-expert FFN, combine, resid}.
// BM=64 (grid 512), 16 waves (2M x 8N, wave 32x32), BK=32.  W from wave-
// contiguous WX; wf register dbuf; setprio (T5).  64KB LDS, 2 blocks/CU.
// NOTE: VGPR=64 is exactly the 8-wave/SIMD budget — do not add registers.
// ---------------------------------------------------------------------------
__global__ __launch_bounds__(1024, 4) void ffn4(
    const u16* __restrict__ Xin, const u16* __restrict__ WX,
    int wPslot, int wbase, const float* __restrict__ bP,
    const float* __restrict__ b1, const float* __restrict__ b2,
    const float* __restrict__ b3, const float* __restrict__ scores,
    const float* __restrict__ csrc, float* __restrict__ outf) {
  __shared__ int4 xsh[2048];   // 32KB: x (proj output) 64x256, chunk-XOR8
  __shared__ int4 hsh[2048];   // 32KB: Xin staging, then h (in-place)
  const int tid = threadIdx.x, wave = tid >> 6, lane = tid & 63;
  const int wm = (wave >> 3) * 32;   // 0 or 32
  const int wn8 = wave & 7;          // N-group: cols wn8*32 .. wn8*32+31
  const int lr = lane & 15, lk = lane >> 4;
  const long m0 = (long)blockIdx.x * 64;

  // stage Xin (64 x 256 bf16) into hsh
#pragma unroll
  for (int it = 0; it < 2; ++it) {
    const int s = tid + it * 1024;
    const int row = s >> 5, c8 = s & 31;
    const int cs = (c8 & 24) | ((c8 ^ row) & 7);
    hsh[row * 32 + cs] = *(const int4*)(Xin + (m0 + row) * 256 + c8 * 8);
  }
  __syncthreads();

  f32x4 acc[2][2];

  // ---- proj layer: x = Xin @ Wo^T + bP -> xsh (no gelu) ----
  {
    const u16* wp = WX + (((long)wPslot) << 16) + (wn8 << 13) + lane * 8;
#pragma unroll
    for (int m = 0; m < 2; ++m)
#pragma unroll
      for (int n = 0; n < 2; ++n) acc[m][n] = f32x4{0.f, 0.f, 0.f, 0.f};
    bs8 wf[2], wfn[2];
    wf[0] = *(const bs8*)(wp);
    wf[1] = *(const bs8*)(wp + 512);
#pragma unroll
    for (int kt = 0; kt < 8; ++kt) {
      if (kt < 7) {
        wfn[0] = *(const bs8*)(wp + (kt + 1) * 1024);
        wfn[1] = *(const bs8*)(wp + (kt + 1) * 1024 + 512);
      }
      bs8 af[2];
      const int c8 = kt * 4 + lk;
#pragma unroll
      for (int m = 0; m < 2; ++m) {
        const int row = wm + m * 16 + lr;
        const int cs = (c8 & 24) | ((c8 ^ row) & 7);
        af[m] = *(const bs8*)&hsh[row * 32 + cs];
      }
      __builtin_amdgcn_s_setprio(1);
#pragma unroll
      for (int m = 0; m < 2; ++m)
#pragma unroll
        for (int n = 0; n < 2; ++n)
          acc[m][n] = __builtin_amdgcn_mfma_f32_16x16x32_bf16(
              af[m], wf[n], acc[m][n], 0, 0, 0);
      __builtin_amdgcn_s_setprio(0);
      wf[0] = wfn[0]; wf[1] = wfn[1];
    }
    // write x to xsh (no hazard: xsh untouched so far)
    u16* xp = (u16*)xsh;
#pragma unroll
    for (int m = 0; m < 2; ++m)
#pragma unroll
      for (int n = 0; n < 2; ++n) {
        const int col = wn8 * 32 + n * 16 + lr;
        const float bv = bP[col];
        const int c8w = col >> 3;
#pragma unroll
        for (int j = 0; j < 4; ++j) {
          const int row = wm + m * 16 + lk * 4 + j;
          const int cs = (c8w & 24) | ((c8w ^ row) & 7);
          xp[row * 256 + cs * 8 + (col & 7)] = f2bf(acc[m][n][j] + bv);
        }
      }
    __syncthreads();   // xsh visible to all waves
  }

  f32x4 oacc[2][2];
#pragma unroll
  for (int m = 0; m < 2; ++m)
#pragma unroll
    for (int n = 0; n < 2; ++n) oacc[m][n] = f32x4{0.f, 0.f, 0.f, 0.f};

  for (int e = 0; e < 4; ++e) {
#pragma unroll 1
    for (int l = 0; l < 3; ++l) {
      const u16* wp = WX + (((long)(wbase + l * 4 + e)) << 16) +
                      (wn8 << 13) + lane * 8;
      const int4* asrc = (l == 0) ? xsh : hsh;
#pragma unroll
      for (int m = 0; m < 2; ++m)
#pragma unroll
        for (int n = 0; n < 2; ++n) acc[m][n] = f32x4{0.f, 0.f, 0.f, 0.f};
      bs8 wf[2], wfn[2];
      wf[0] = *(const bs8*)(wp);
      wf[1] = *(const bs8*)(wp + 512);
#pragma unroll
      for (int kt = 0; kt < 8; ++kt) {
        if (kt < 7) {   // prefetch kt+1 fragments (covered by MFMA below)
          wfn[0] = *(const bs8*)(wp + (kt + 1) * 1024);
          wfn[1] = *(const bs8*)(wp + (kt + 1) * 1024 + 512);
        }
        bs8 af[2];
        const int c8 = kt * 4 + lk;
#pragma unroll
        for (int m = 0; m < 2; ++m) {
          const int row = wm + m * 16 + lr;
          const int cs = (c8 & 24) | ((c8 ^ row) & 7);
          af[m] = *(const bs8*)&asrc[row * 32 + cs];
        }
        __builtin_amdgcn_s_setprio(1);
#pragma unroll
        for (int m = 0; m < 2; ++m)
#pragma unroll
          for (int n = 0; n < 2; ++n)
            acc[m][n] = __builtin_amdgcn_mfma_f32_16x16x32_bf16(
                af[m], wf[n], acc[m][n], 0, 0, 0);
        __builtin_amdgcn_s_setprio(0);
        wf[0] = wfn[0]; wf[1] = wfn[1];
      }
      if (l < 2) {
        __syncthreads();   // all asrc reads done before hsh overwrite
        const float* bb = (l == 0 ? b1 : b2) + e * 256;
        u16* hp = (u16*)hsh;
#pragma unroll
        for (int m = 0; m < 2; ++m)
#pragma unroll
          for (int n = 0; n < 2; ++n) {
            const int col = wn8 * 32 + n * 16 + lr;
            const float bv = bb[col];
            const int c8w = col >> 3;
#pragma unroll
            for (int j = 0; j < 4; ++j) {
              const int row = wm + m * 16 + lk * 4 + j;
              const int cs = (c8w & 24) | ((c8w ^ row) & 7);
              hp[row * 256 + cs * 8 + (col & 7)] =
                  f2bf(gelu_f(acc[m][n][j] + bv));
            }
          }
        __syncthreads();   // hsh visible to next layer
      } else {  // + b3, score-weighted accumulate (registers only)
#pragma unroll
        for (int m = 0; m < 2; ++m) {
#pragma unroll
          for (int j = 0; j < 4; ++j) {
            const float sc = scores[(m0 + wm + m * 16 + lk * 4 + j) * 4 + e];
#pragma unroll
            for (int n = 0; n < 2; ++n)
              oacc[m][n][j] +=
                  sc * (acc[m][n][j] + b3[e * 256 + wn8 * 32 + n * 16 + lr]);
          }
        }
      }
    }
  }
#pragma unroll
  for (int m = 0; m < 2; ++m) {
#pragma unroll
    for (int n = 0; n < 2; ++n) {
      const int col = wn8 * 32 + n * 16 + lr;
#pragma unroll
      for (int j = 0; j < 4; ++j) {
        const long idx = (m0 + wm + m * 16 + lk * 4 + j) * 256 + col;
        outf[idx] = csrc[idx] + oacc[m][n][j];
      }
    }
  }
}

// ---------------------------------------------------------------------------
// kvstats (merged-f): fused {K-proj, V-proj, K-softmax, per-head stats}.
// blockIdx.y = fb = f*4 + b.  Partials ptm stored as BF16 (halves the
// kvstats->reduce round-trip traffic; error << absmax margin).
// ---------------------------------------------------------------------------
__global__ __launch_bounds__(1024, 4) void kvstats(
    const float* __restrict__ A0, const float* __restrict__ A1,
    const u16* __restrict__ Wk0, const u16* __restrict__ Wk1,
    const u16* __restrict__ Wv0, const u16* __restrict__ Wv1,
    const float* __restrict__ bk0, const float* __restrict__ bk1,
    const float* __restrict__ bv0, const float* __restrict__ bv1,
    float* __restrict__ pks, u16* __restrict__ ptm) {
  __shared__ __align__(16) char smem[73728];
  int4* ash  = (int4*)smem;        // 512 slots  (64x64 bf16)
  int4* wksh = ash + 512;          // 2048 slots (256x64)
  int4* wvsh = wksh + 2048;        // 2048 slots
  u16* KnT = (u16*)smem;           // [256][72] bf16 (transposed, padded)
  u16* VT  = KnT + 256 * 72;
  const int tid = threadIdx.x;
  const int wave = tid >> 6, lane = tid & 63;
  const int lr = lane & 15, lk = lane >> 4;
  const int kvsel = wave >> 3, w3 = wave & 7;
  const int wm = (w3 >> 2) * 32, wn = (w3 & 3) * 64;
  const int fb = blockIdx.y, ch = blockIdx.x;
  const int f = fb >> 2, b = fb & 3;
  const float* Ain = f ? A1 : A0;
  const u16* Wk = f ? Wk1 : Wk0;
  const u16* Wv = f ? Wv1 : Wv0;
  const float* bk = f ? bk1 : bk0;
  const float* bv = f ? bv1 : bv0;
  const long r0 = (long)b * 8192 + (long)ch * 64;

  f32x4 acc[2][4];
#pragma unroll
  for (int m = 0; m < 2; ++m)
#pragma unroll
    for (int n = 0; n < 4; ++n) acc[m][n] = f32x4{0.f, 0.f, 0.f, 0.f};

  for (int kt = 0; kt < 4; ++kt) {
    const int k0 = kt * 64;
    if (kt) __syncthreads();
    if (tid < 512) {  // A tile 64x64 fp32 -> bf16
      const int row = tid >> 3, c16 = tid & 7;
      const int dst = (row << 3) | (c16 ^ (row & 7));
      const float4* p = (const float4*)(Ain + (r0 + row) * 256 + k0 + c16 * 8);
      const float4 x = p[0], y = p[1];
      int4 val;
      val.x = pack2(x.x, x.y); val.y = pack2(x.z, x.w);
      val.z = pack2(y.x, y.y); val.w = pack2(y.z, y.w);
      ash[dst] = val;
    }
#pragma unroll
    for (int it = 0; it < 2; ++it) {  // Wk + Wv tiles 256x64
      const int s = tid + it * 1024;
      const int row = s >> 3, c16 = s & 7;
      const int dst = (row << 3) | (c16 ^ (row & 7));
      wksh[dst] = *(const int4*)(Wk + (long)row * 256 + k0 + c16 * 8);
      wvsh[dst] = *(const int4*)(Wv + (long)row * 256 + k0 + c16 * 8);
    }
    __syncthreads();
    const int4* wsh = kvsel ? wvsh : wksh;
#pragma unroll
    for (int kk = 0; kk < 2; ++kk) {
      bs8 af[2], wf[4];
#pragma unroll
      for (int m = 0; m < 2; ++m) {
        const int row = wm + m * 16 + lr;
        af[m] = *(const bs8*)&ash[(row << 3) | ((kk * 4 + lk) ^ (row & 7))];
      }
#pragma unroll
      for (int n = 0; n < 4; ++n) {
        const int row = wn + n * 16 + lr;
        wf[n] = *(const bs8*)&wsh[(row << 3) | ((kk * 4 + lk) ^ (row & 7))];
      }
#pragma unroll
      for (int m = 0; m < 2; ++m)
#pragma unroll
        for (int n = 0; n < 4; ++n)
          acc[m][n] = __builtin_amdgcn_mfma_f32_16x16x32_bf16(af[m], wf[n],
                                                              acc[m][n], 0, 0, 0);
    }
  }
  __syncthreads();  // GEMM LDS dead; reuse as KnT/VT

  const float* bias = kvsel ? bv : bk;
  if (kvsel == 0) {
#pragma unroll
    for (int m = 0; m < 2; ++m)
#pragma unroll
      for (int j = 0; j < 4; ++j)
#pragma unroll
        for (int hh = 0; hh < 2; ++hh) {
          const int c0 = wn + (2 * hh) * 16 + lr;
          const float p0 = __expf(acc[m][2 * hh][j] + bias[c0]);
          const float p1 = __expf(acc[m][2 * hh + 1][j] + bias[c0 + 16]);
          float s = p0 + p1;
#pragma unroll
          for (int o = 8; o >= 1; o >>= 1) s += __shfl_xor(s, o);
          const float inv = 1.0f / s;
          acc[m][2 * hh][j] = p0 * inv;
          acc[m][2 * hh + 1][j] = p1 * inv;
        }
  }
  {
    u16* T = kvsel ? VT : KnT;
#pragma unroll
    for (int m = 0; m < 2; ++m) {
      const int rb = wm + m * 16 + lk * 4;
#pragma unroll
      for (int n = 0; n < 4; ++n) {
        const int col = wn + n * 16 + lr;
        float v0 = acc[m][n][0], v1 = acc[m][n][1];
        float v2 = acc[m][n][2], v3 = acc[m][n][3];
        if (kvsel) {
          const float bb = bias[col];
          v0 += bb; v1 += bb; v2 += bb; v3 += bb;
        }
        uint2 w;
        w.x = pack2(v0, v1); w.y = pack2(v2, v3);
        *(uint2*)(T + col * 72 + rb) = w;
      }
    }
  }
  __syncthreads();

  if (kvsel == 0) {  // stats: wave w3 = head h
    const int h = w3;
    f32x16 aT, aK;
#pragma unroll
    for (int r = 0; r < 16; ++r) { aT[r] = 0.f; aK[r] = 0.f; }
    bs8 ones;
#pragma unroll
    for (int e = 0; e < 8; ++e) ones[e] = (short)0x3F80;
    const u16* kcol = KnT + (h * 32 + (lane & 31)) * 72;
    const u16* vcol = VT  + (h * 32 + (lane & 31)) * 72;
    const int hi8 = (lane >> 5) * 8;
#pragma unroll
    for (int ks = 0; ks < 4; ++ks) {
      const bs8 a  = *(const bs8*)(kcol + ks * 16 + hi8);
      const bs8 vb = *(const bs8*)(vcol + ks * 16 + hi8);
      aT = __builtin_amdgcn_mfma_f32_32x32x16_bf16(vb, a, aT, 0, 0, 0);  // tmpT
      aK = __builtin_amdgcn_mfma_f32_32x32x16_bf16(a, ones, aK, 0, 0, 0);
    }
    const long blk = (long)fb * gridDim.x + ch;
    u16* po = ptm + blk * 8192 + h * 1024;
#pragma unroll
    for (int r = 0; r < 16; ++r) {
      const int dv = (r & 3) + 8 * (r >> 2) + 4 * (lane >> 5);
      po[dv * 32 + (lane & 31)] = f2bf(aT[r]);   // tmpT[h][dv][dk], bf16
    }
    if ((lane & 31) == 0) {
#pragma unroll
      for (int r = 0; r < 16; ++r) {
        const int dk = (r & 3) + 8 * (r >> 2) + 4 * (lane >> 5);
        pks[blk * 256 + h * 32 + dk] = aK[r];
      }
    }
  }
}

// deterministic reduce of the 128 chunk-partials per fb (blockIdx.y)
// ptm partials are bf16; accumulate in fp32.
__global__ void reduceStats(const float* __restrict__ pk,
                            const u16* __restrict__ pt,
                            float* __restrict__ ksum, float* __restrict__ tmp) {
  const int b = blockIdx.y;
  const int i = blockIdx.x * 256 + threadIdx.x;  // 0..8447
  float s = 0.f;
  if (i < 256) {
    const float* p = pk + (long)b * 128 * 256 + i;
    for (int c = 0; c < 128; ++c) s += p[c * 256];
    ksum[(long)b * 256 + i] = s;
  } else {
    const int j = i - 256;
    const u16* p = pt + (long)b * 128 * 8192 + j;
    for (int c = 0; c < 128; ++c) s += bf2f(p[c * 8192]);
    tmp[(long)b * 8192 + j] = s;
  }
}

// ---------------------------------------------------------------------------
// mixk (shfl-free): out = q + (1/F) sum_f alpha_f * (q @ tmp_f)
// ---------------------------------------------------------------------------
template <int F>
__global__ __launch_bounds__(256, 2) void mixk(const u16* __restrict__ q,
                                               const float* __restrict__ ksum,
                                               const float* __restrict__ tmp,
                                               u16* __restrict__ out) {
  constexpr int LF = (F == 2) ? 1 : 0;
  constexpr int QS = 264;               // u16 row stride (528 B, 16B-aligned)
  __shared__ u16 qsh[64 * QS];
  __shared__ float alsh[64][17];
  __shared__ float ksh[8][F * 36];      // padded per-head ksum
  const int t = threadIdx.x;
  const int h = t >> 5, dv = t & 31;
  const int b = blockIdx.y;
  const long row0 = (long)b * 8192 + (long)blockIdx.x * 64;

#pragma unroll
  for (int it = 0; it < 8; ++it) {
    const int i = t + it * 256;
    const int r = i >> 5, c = i & 31;
    *(int4*)&qsh[r * QS + c * 8] = *(const int4*)&q[(row0 + r) * 256 + c * 8];
  }
#pragma unroll
  for (int f = 0; f < F; ++f)
    ksh[h][f * 36 + dv] = ksum[((long)f * 4 + b) * 256 + t];
  float tr[F][32];
#pragma unroll
  for (int f = 0; f < F; ++f) {
    const float* tp = tmp + ((long)f * 4 + b) * 8192 + h * 1024 + dv * 32;
#pragma unroll
    for (int c = 0; c < 8; ++c) {
      const float4 v = *(const float4*)(tp + c * 4);
      tr[f][c * 4] = v.x; tr[f][c * 4 + 1] = v.y;
      tr[f][c * 4 + 2] = v.z; tr[f][c * 4 + 3] = v.w;
    }
  }
  __syncthreads();

  for (int d = t; d < 64 * 8 * F; d += 256) {
    const int f = d & (F - 1);
    const int hh = (d >> LF) & 7;
    const int r = d >> (3 + LF);
    const u16* qp = &qsh[r * QS + hh * 32];
    const float* kp = &ksh[hh][f * 36];
    float s = 0.f;
#pragma unroll
    for (int c = 0; c < 4; ++c) {
      const bs8 qa = *(const bs8*)(qp + c * 8);
#pragma unroll
      for (int j = 0; j < 8; ++j) s += bf2f((u16)qa[j]) * kp[c * 8 + j];
    }
    alsh[r][(hh << LF) | f] = 1.0f / s;
  }
  __syncthreads();

#pragma unroll 2
  for (int r = 0; r < 64; ++r) {
    float qr[32];
    const u16* qp = &qsh[r * QS + h * 32];
#pragma unroll
    for (int c = 0; c < 4; ++c) {
      const bs8 qa = *(const bs8*)(qp + c * 8);
#pragma unroll
      for (int j = 0; j < 8; ++j) qr[c * 8 + j] = bf2f((u16)qa[j]);
    }
    float acc = 0.f;
#pragma unroll
    for (int f = 0; f < F; ++f) {
      float s0 = 0.f, s1 = 0.f;
#pragma unroll
      for (int dk = 0; dk < 32; dk += 2) {
        s0 += qr[dk] * tr[f][dk];
        s1 += qr[dk + 1] * tr[f][dk + 1];
      }
      acc += (s0 + s1) * alsh[r][(h << LF) | f];
    }
    const float qv = bf2f(qsh[r * QS + t]);
    out[(row0 + r) * 256 + t] = f2bf(qv + acc * (1.0f / (float)F));
  }
}

// pre-convert the 10 attention (256x256) weight matrices to bf16 (row-major)
struct WTab10 { const float* p[10]; };
__global__ void convW(WTab10 tab, u16* __restrict__ dst) {
  const int s = blockIdx.y;
  const long i = ((long)blockIdx.x * 256 + threadIdx.x) * 4;
  const float4 v = *(const float4*)(tab.p[s] + i);
  ushort4 o;
  o.x = f2bf(v.x); o.y = f2bf(v.y); o.z = f2bf(v.z); o.w = f2bf(v.w);
  *(ushort4*)(dst + (long)s * 65536 + i) = o;
}

// pre-convert 26 matrices (24 FFN + ca_Wo + sa_Wo) to WAVE-CONTIGUOUS order:
// WX[s][wn8(8)][kt(8)][n(2)][lane(64)][8],
//   row = wn8*32 + n*16 + (lane&15), col = kt*32 + (lane>>4)*8 + j
struct WTab26 { const float* p[26]; };
__global__ void convWX(WTab26 tab, u16* __restrict__ dst) {
  const int s = blockIdx.y;
  const int o8 = blockIdx.x * 256 + threadIdx.x;   // 0..8191
  const int lane = o8 & 63;
  const int n = (o8 >> 6) & 1;
  const int kt = (o8 >> 7) & 7;
  const int wn8 = o8 >> 10;
  const int row = wn8 * 32 + n * 16 + (lane & 15);
  const int col = kt * 32 + (lane >> 4) * 8;
  const float* src = tab.p[s] + row * 256 + col;
  const float4 a = *(const float4*)src;
  const float4 b = *(const float4*)(src + 4);
  int4 val;
  val.x = pack2(a.x, a.y); val.y = pack2(a.z, a.w);
  val.z = pack2(b.x, b.y); val.w = pack2(b.z, b.w);
  *(int4*)(dst + (long)s * 65536 + (long)o8 * 8) = val;
}

// ---------------------------------------------------------------------------
extern "C" void kernel_launch(void* const* d_in, const int* in_sizes, int n_in,
                              void* d_out, int out_size, void* d_ws, size_t ws_size,
                              hipStream_t stream) {
  (void)in_sizes; (void)n_in; (void)out_size; (void)ws_size;
  const float* scores = (const float*)d_in[0];
  const float* query  = (const float*)d_in[1];
  const float* IF     = (const float*)d_in[2];
  const float* ca_Wq = (const float*)d_in[3];  const float* ca_bq = (const float*)d_in[4];
  const float* ca_Wk = (const float*)d_in[5];  const float* ca_bk = (const float*)d_in[6];
  const float* ca_Wv = (const float*)d_in[7];  const float* ca_bv = (const float*)d_in[8];
  const float* ca_Wo = (const float*)d_in[9];  const float* ca_bo = (const float*)d_in[10];
  const float* sa_Wq = (const float*)d_in[11]; const float* sa_bq = (const float*)d_in[12];
  const float* sa_Wk = (const float*)d_in[13]; const float* sa_bk = (const float*)d_in[14];
  const float* sa_Wv = (const float*)d_in[15]; const float* sa_bv = (const float*)d_in[16];
  const float* sa_Wo = (const float*)d_in[17]; const float* sa_bo = (const float*)d_in[18];
  const float* f1W1 = (const float*)d_in[19]; const float* f1b1 = (const float*)d_in[20];
  const float* f1W2 = (const float*)d_in[21]; const float* f1b2 = (const float*)d_in[22];
  const float* f1W3 = (const float*)d_in[23]; const float* f1b3 = (const float*)d_in[24];
  const float* f2W1 = (const float*)d_in[25]; const float* f2b1 = (const float*)d_in[26];
  const float* f2W2 = (const float*)d_in[27]; const float* f2b2 = (const float*)d_in[28];
  const float* f2W3 = (const float*)d_in[29]; const float* f2b3 = (const float*)d_in[30];

  char* ws = (char*)d_ws;
  u16* X0 = (u16*)(ws);                   // (M,256) bf16
  u16* X1 = (u16*)(ws + 16777216);        // mix output (also ptmBig region)
  u16* ptmBig = (u16*)(ws + 16777216);    // kvstats bf16 partials (<=16.8MB)
  u16* W16 = (u16*)(ws + 67108864);       // 10 * 65536 bf16
  u16* WX  = (u16*)(ws + 68419584);       // 26 * 65536 bf16 = 3.4 MB
  float* ksum = (float*)(ws + 71827456);  // [8][256]
  float* tmpb = (float*)(ws + 71835648);  // [8][8192]
  float* pks  = (float*)(ws + 72097792);  // [8][128][256] = 1 MB
  float* qacc = (float*)d_out;            // fp32 accumulator = output

  WTab10 tab;
  tab.p[0] = ca_Wq; tab.p[1] = ca_Wk; tab.p[2] = ca_Wk + 65536;
  tab.p[3] = ca_Wv; tab.p[4] = ca_Wv + 65536; tab.p[5] = ca_Wo;
  tab.p[6] = sa_Wq; tab.p[7] = sa_Wk; tab.p[8] = sa_Wv; tab.p[9] = sa_Wo;
  convW<<<dim3(64, 10), 256, 0, stream>>>(tab, W16);

  WTab26 tabx;
  for (int e = 0; e < 4; ++e) {
    tabx.p[0 + e]  = f1W1 + e * 65536;
    tabx.p[4 + e]  = f1W2 + e * 65536;
    tabx.p[8 + e]  = f1W3 + e * 65536;
    tabx.p[12 + e] = f2W1 + e * 65536;
    tabx.p[16 + e] = f2W2 + e * 65536;
    tabx.p[20 + e] = f2W3 + e * 65536;
  }
  tabx.p[24] = ca_Wo;
  tabx.p[25] = sa_Wo;
  convWX<<<dim3(32, 26), 256, 0, stream>>>(tabx, WX);

  const dim3 gg(512, 2), gb(256);
  // ---- cross attention ----
  gemm256<true, EPI_QSM><<<gg, gb, 0, stream>>>(query, W16 + 0 * 65536L, ca_bq, X0);
  kvstats<<<dim3(128, 8), 1024, 0, stream>>>(
      IF, IF + 8388608L,
      W16 + 1 * 65536L, W16 + 2 * 65536L, W16 + 3 * 65536L, W16 + 4 * 65536L,
      ca_bk, ca_bk + 256, ca_bv, ca_bv + 256, pks, ptmBig);
  reduceStats<<<dim3(33, 8), 256, 0, stream>>>(pks, ptmBig, ksum, tmpb);
  mixk<2><<<dim3(128, 4), 256, 0, stream>>>(X0, ksum, tmpb, X1);
  ffn4<<<512, 1024, 0, stream>>>(X1, WX, 24, 0, ca_bo,
                                 f1b1, f1b2, f1b3, scores, query, qacc);
  // ---- self attention ----
  gemm256<true, EPI_QSM><<<gg, gb, 0, stream>>>(qacc, W16 + 6 * 65536L, sa_bq, X0);
  kvstats<<<dim3(128, 4), 1024, 0, stream>>>(
      qacc, qacc,
      W16 + 7 * 65536L, W16 + 7 * 65536L, W16 + 8 * 65536L, W16 + 8 * 65536L,
      sa_bk, sa_bk, sa_bv, sa_bv, pks, ptmBig);
  reduceStats<<<dim3(33, 4), 256, 0, stream>>>(pks, ptmBig, ksum, tmpb);
  mixk<1><<<dim3(128, 4), 256, 0, stream>>>(X0, ksum, tmpb, X1);
  ffn4<<<512, 1024, 0, stream>>>(X1, WX, 25, 12, sa_bo,
                                 f2b1, f2b2, f2b3, scores, qacc, qacc);
}